// Round 5
// baseline (203.625 us; speedup 1.0000x reference)
//
#include <hip/hip_runtime.h>
#include <hip/hip_bf16.h>

using bf16 = __hip_bfloat16;
using bf16x8 = __attribute__((ext_vector_type(8))) short;
using f32x4 = __attribute__((ext_vector_type(4))) float;

#define LOG2E 1.44269504088896f

__device__ __forceinline__ void gload_lds16(const void* g, void* lds) {
    __builtin_amdgcn_global_load_lds(
        (const __attribute__((address_space(1))) void*)g,
        (__attribute__((address_space(3))) void*)lds, 16, 0, 0);
}

// ---------------- fused fp32 -> bf16 convert for all 7 tensors --------
struct __align__(16) BH8 { bf16 h[8]; };
struct __align__(8)  BH4 { bf16 h[4]; };

struct CvtArgs { const float* src[7]; BH8* dst[7]; };

// vec8 counts: q,k,v = 524288 each (pow2), W_* = 131072 each (pow2)
__global__ __launch_bounds__(256) void cvt_all(CvtArgs ca) {
    int i = blockIdx.x * 256 + threadIdx.x;   // vec8 index, total 2097152
    const float* src; BH8* dst; int off;
    if (i < 3 * 524288) {
        int w = i >> 19; off = i & 524287;
        src = ca.src[w]; dst = ca.dst[w];
    } else {
        int j = i - 3 * 524288;
        int w = 3 + (j >> 17); off = j & 131071;
        src = ca.src[w]; dst = ca.dst[w];
    }
    const float4* p = (const float4*)src + (size_t)off * 2;
    float4 a = p[0], b = p[1];
    BH8 r;
    r.h[0] = __float2bfloat16(a.x); r.h[1] = __float2bfloat16(a.y);
    r.h[2] = __float2bfloat16(a.z); r.h[3] = __float2bfloat16(a.w);
    r.h[4] = __float2bfloat16(b.x); r.h[5] = __float2bfloat16(b.y);
    r.h[6] = __float2bfloat16(b.z); r.h[7] = __float2bfloat16(b.w);
    dst[off] = r;
}

// ---------------- RoPE tables: cos/sin per (s, pair i) ----------------
__global__ __launch_bounds__(256) void rope_tables(float* __restrict__ ct,
                                                   float* __restrict__ st) {
    int idx = blockIdx.x * 256 + threadIdx.x;
    if (idx >= 2048 * 512) return;
    int s = idx >> 9, i = idx & 511;
    // theta = 10000^(-2i/1024) = exp2(i * (-2/1024)*log2(10000))
    float theta = exp2f((float)i * -0.0259525632413075f);
    float ang = (float)s * theta;
    ct[idx] = cosf(ang);
    st[idx] = sinf(ang);
}

// ---------------- GEMM C = A * W^T (A:[M][1024], W:[1024][1024]) ------
// MF = m-fragments per wave; block tile = (MF*32) x 128, 4 waves (2m x 2n)
// mode 0: +bias, fp32 out [M][1024]
// mode 1: RoPE + (0.125*log2e) scale, bf16 head-split out [bh][s][64]  (Q)
// mode 2: RoPE,               bf16 head-split out [bh][s][64]   (K)
// mode 3: plain,              bf16 transposed  out [bh][64][s]  (V^T)
struct ProjArgs {
    const bf16* A[3];
    const bf16* W[3];
    void* out[3];
    int mode[3];
};

template <int MF>
__global__ __launch_bounds__(256, 2) void gemm_bt(ProjArgs pa,
        const float* __restrict__ ct, const float* __restrict__ st,
        const float* __restrict__ bias) {
    constexpr int Kd = 1024;
    constexpr int BM = MF * 32;
    __shared__ __align__(16) bf16 As[BM * 32];
    __shared__ __align__(16) bf16 Bs[128 * 32];
    const int z = blockIdx.z;
    const bf16* __restrict__ A = pa.A[z];
    const bf16* __restrict__ W = pa.W[z];
    const int mode = pa.mode[z];
    const int tid = threadIdx.x, wid = tid >> 6, lane = tid & 63;
    const int g = lane >> 4, l15 = lane & 15;
    const int wm = wid >> 1, wn = wid & 1;
    const int m0 = blockIdx.y * BM, n0 = blockIdx.x * 128;
    f32x4 acc[MF][4] = {};
    const int sbyte = wid * 1024 + lane * 16;

    for (int kb = 0; kb < Kd; kb += 32) {
        __syncthreads();
#pragma unroll
        for (int r = 0; r < MF / 2; ++r) {
            int byte = sbyte + r * 4096;
            int row = byte >> 6, cb = byte & 63;
            int csrc = cb ^ (((row >> 1) & 3) << 4);   // XOR-swizzle on global source
            gload_lds16((const char*)(A + (size_t)(m0 + row) * Kd + kb) + csrc,
                        (char*)As + wid * 1024 + r * 4096);
        }
#pragma unroll
        for (int r = 0; r < 2; ++r) {
            int byte = sbyte + r * 4096;
            int row = byte >> 6, cb = byte & 63;
            int csrc = cb ^ (((row >> 1) & 3) << 4);
            gload_lds16((const char*)(W + (size_t)(n0 + row) * Kd + kb) + csrc,
                        (char*)Bs + wid * 1024 + r * 4096);
        }
        __syncthreads();
        bf16x8 af[MF], bw[4];
#pragma unroll
        for (int i = 0; i < MF; ++i) {
            int ra = wm * (MF * 16) + i * 16 + l15;
            af[i] = *(const bf16x8*)((const char*)As + ra * 64 +
                                     ((g * 16) ^ (((ra >> 1) & 3) << 4)));
        }
#pragma unroll
        for (int j = 0; j < 4; ++j) {
            int rb = wn * 64 + j * 16 + l15;
            bw[j] = *(const bf16x8*)((const char*)Bs + rb * 64 +
                                     ((g * 16) ^ (((rb >> 1) & 3) << 4)));
        }
#pragma unroll
        for (int i = 0; i < MF; ++i)
#pragma unroll
            for (int j = 0; j < 4; ++j)
                acc[i][j] = __builtin_amdgcn_mfma_f32_16x16x32_bf16(af[i], bw[j], acc[i][j], 0, 0, 0);
    }

    if (mode == 0) {
        float* out = (float*)pa.out[z];
#pragma unroll
        for (int i = 0; i < MF; ++i) {
            int row = m0 + wm * (MF * 16) + i * 16 + g * 4;
#pragma unroll
            for (int j = 0; j < 4; ++j) {
                int col = n0 + wn * 64 + j * 16 + l15;
                float bv = bias[col];
#pragma unroll
                for (int r = 0; r < 4; ++r)
                    out[(size_t)(row + r) * 1024 + col] = acc[i][j][r] + bv;
            }
        }
    } else if (mode == 3) {
        bf16* out = (bf16*)pa.out[z];
#pragma unroll
        for (int i = 0; i < MF; ++i) {
            int m = m0 + wm * (MF * 16) + i * 16 + g * 4;
            int b = m >> 11, s = m & 2047;
#pragma unroll
            for (int j = 0; j < 4; ++j) {
                int col = n0 + wn * 64 + j * 16 + l15;
                int h = col >> 6, dv = col & 63;
                BH4 pk;
#pragma unroll
                for (int r = 0; r < 4; ++r) pk.h[r] = __float2bfloat16(acc[i][j][r]);
                *(BH4*)(out + (((size_t)(b * 16 + h)) * 64 + dv) * 2048 + s) = pk;
            }
        }
    } else {  // RoPE modes
        bf16* out = (bf16*)pa.out[z];
        float scl = (mode == 1) ? (0.125f * LOG2E) : 1.0f;
#pragma unroll
        for (int i = 0; i < MF; ++i) {
            int mrow = m0 + wm * (MF * 16) + i * 16 + g * 4;
#pragma unroll
            for (int j = 0; j < 4; ++j) {
                int col = n0 + wn * 64 + j * 16 + l15;
                int ci = col >> 1;
                float sgn = (col & 1) ? -1.0f : 1.0f;
                int h = col >> 6, dv = col & 63;
#pragma unroll
                for (int r = 0; r < 4; ++r) {
                    int m = mrow + r;
                    int b = m >> 11, s = m & 2047;
                    float vv = acc[i][j][r];
                    float pv = __shfl_xor(vv, 1);     // paired column lives in lane^1
                    float c = ct[s * 512 + ci], sn = st[s * 512 + ci];
                    float o = (vv * c + sgn * sn * pv) * scl;
                    out[(((size_t)(b * 16 + h)) * 2048 + s) * 64 + dv] = __float2bfloat16(o);
                }
            }
        }
    }
}

// -------- flash attention, register-direct: no LDS, no barriers --------
// Each wave owns 32 q-rows independently. Fixed-max softmax (m=0) makes
// waves stateless. Swapped QK^T (S^T = K x Q) + permuted K-row loading
// makes the PV A-operand lane-local (zero-cost P re-layout).
// K-row permutation: A-row a of fragment kfr holds physical k-row
//   pi(kfr,a) = 32*(kfr>>1) + 8*(a>>2) + 4*(kfr&1) + (a&3)
// so lane (q=l15,g) register r of frag kfr = P[q][32*(kfr>>1)+8g+4*(kfr&1)+r],
// i.e. PV-chunk a elems 0-3 = frag 2a regs 0-3, elems 4-7 = frag 2a+1 regs 0-3.
__global__ __launch_bounds__(256, 2) void attn_fwd(
        const bf16* __restrict__ Qh, const bf16* __restrict__ Kh,
        const bf16* __restrict__ Vt, bf16* __restrict__ Y) {
    const int tid = threadIdx.x, wid = tid >> 6, lane = tid & 63;
    const int g = lane >> 4, l15 = lane & 15;
    // XCD swizzle: blocks of one bh colocate on an XCD (K/V stays in its L2)
    const int lin = blockIdx.y * 16 + blockIdx.x;   // 0..511
    const int swz = (lin & 7) * 64 + (lin >> 3);
    const int bh = swz >> 4, qt = swz & 15;
    const int q0 = qt * 128 + wid * 32;
    const bf16* Qb = Qh + (size_t)bh * 2048 * 64;
    const bf16* Kb = Kh + (size_t)bh * 2048 * 64;
    const bf16* Vb = Vt + (size_t)bh * 64 * 2048;

    // Q fragments (B-operand): [qfr][d-chunk kk]
    bf16x8 aq[2][2];
#pragma unroll
    for (int qfr = 0; qfr < 2; ++qfr)
#pragma unroll
        for (int kk = 0; kk < 2; ++kk)
            aq[qfr][kk] = *(const bf16x8*)(Qb + (size_t)(q0 + qfr * 16 + l15) * 64 + kk * 32 + g * 8);

    // permuted K row index per fragment (A-row = l15 at load time)
    int prow[4];
#pragma unroll
    for (int kfr = 0; kfr < 4; ++kfr)
        prow[kfr] = ((kfr >> 1) << 5) + ((l15 >> 2) << 3) + ((kfr & 1) << 2) + (l15 & 3);

    f32x4 yacc[2][4] = {};          // [qfr][dn]: row q=qfr*16+4g+r, col dv=dn*16+l15
    float lrow[2] = {0.f, 0.f};     // per-lane partial row-sum for q = qfr*16+l15

    // K fragments for tile 0
    bf16x8 kf[4][2];
#pragma unroll
    for (int kfr = 0; kfr < 4; ++kfr)
#pragma unroll
        for (int kk = 0; kk < 2; ++kk)
            kf[kfr][kk] = *(const bf16x8*)(Kb + (size_t)prow[kfr] * 64 + kk * 32 + g * 8);

    for (int t = 0; t < 32; ++t) {
        // issue V(t): in flight during QK^T
        bf16x8 vf[4][2];
#pragma unroll
        for (int dn = 0; dn < 4; ++dn)
#pragma unroll
            for (int a = 0; a < 2; ++a)
                vf[dn][a] = *(const bf16x8*)(Vb + (size_t)(dn * 16 + l15) * 2048 + t * 64 + a * 32 + g * 8);

        // QK^T (swapped): sacc[kfr][qfr] = S^T fragments
        f32x4 sacc[4][2] = {};
#pragma unroll
        for (int kk = 0; kk < 2; ++kk)
#pragma unroll
            for (int kfr = 0; kfr < 4; ++kfr)
#pragma unroll
                for (int qfr = 0; qfr < 2; ++qfr)
                    sacc[kfr][qfr] = __builtin_amdgcn_mfma_f32_16x16x32_bf16(
                        kf[kfr][kk], aq[qfr][kk], sacc[kfr][qfr], 0, 0, 0);

        // prefetch K(t+1): in flight during softmax + PV
        bf16x8 kn[4][2];
        if (t < 31) {
#pragma unroll
            for (int kfr = 0; kfr < 4; ++kfr)
#pragma unroll
                for (int kk = 0; kk < 2; ++kk)
                    kn[kfr][kk] = *(const bf16x8*)(Kb + (size_t)((t + 1) * 64 + prow[kfr]) * 64 + kk * 32 + g * 8);
        }

        // softmax numerator (m=0): p = 2^s, pack lane-locally into PV A-frags
        bf16x8 ap[2][2];   // [qfr][a]
#pragma unroll
        for (int qfr = 0; qfr < 2; ++qfr)
#pragma unroll
            for (int a = 0; a < 2; ++a) {
                bf16 h[8];
#pragma unroll
                for (int r = 0; r < 4; ++r) {
                    float x = exp2f(sacc[2 * a][qfr][r]);
                    lrow[qfr] += x;
                    h[r] = __float2bfloat16(x);
                }
#pragma unroll
                for (int r = 0; r < 4; ++r) {
                    float x = exp2f(sacc[2 * a + 1][qfr][r]);
                    lrow[qfr] += x;
                    h[4 + r] = __float2bfloat16(x);
                }
                ap[qfr][a] = *(const bf16x8*)h;
            }

        // PV: yacc[qfr][dn] += P * V
#pragma unroll
        for (int a = 0; a < 2; ++a)
#pragma unroll
            for (int qfr = 0; qfr < 2; ++qfr)
#pragma unroll
                for (int dn = 0; dn < 4; ++dn)
                    yacc[qfr][dn] = __builtin_amdgcn_mfma_f32_16x16x32_bf16(
                        ap[qfr][a], vf[dn][a], yacc[qfr][dn], 0, 0, 0);

        // rotate K
#pragma unroll
        for (int kfr = 0; kfr < 4; ++kfr)
#pragma unroll
            for (int kk = 0; kk < 2; ++kk)
                kf[kfr][kk] = kn[kfr][kk];
    }

    // epilogue: reduce l across g-groups, redistribute, normalize, write
    const int b = bh >> 4, h = bh & 15;
#pragma unroll
    for (int qfr = 0; qfr < 2; ++qfr) {
        float ls = lrow[qfr];
        ls += __shfl_xor(ls, 16);
        ls += __shfl_xor(ls, 32);       // all lanes: l for q = qfr*16 + l15
#pragma unroll
        for (int r = 0; r < 4; ++r) {
            float lv = __shfl(ls, g * 4 + r);   // l for q = qfr*16 + 4g + r
            float inv = 1.0f / lv;
            int s = q0 + qfr * 16 + g * 4 + r;
            bf16* yp = Y + ((size_t)(b * 2048 + s)) * 1024 + h * 64;
#pragma unroll
            for (int dn = 0; dn < 4; ++dn)
                yp[dn * 16 + l15] = __float2bfloat16(yacc[qfr][dn][r] * inv);
        }
    }
}

// ---------------------------------------------------------------------
extern "C" void kernel_launch(void* const* d_in, const int* in_sizes, int n_in,
                              void* d_out, int out_size, void* d_ws, size_t ws_size,
                              hipStream_t stream) {
    const float* q  = (const float*)d_in[0];
    const float* k  = (const float*)d_in[1];
    const float* v  = (const float*)d_in[2];
    const float* Wq = (const float*)d_in[3];
    const float* Wk = (const float*)d_in[4];
    const float* Wv = (const float*)d_in[5];
    const float* Wo = (const float*)d_in[6];
    const float* bo = (const float*)d_in[7];

    const size_t MB = 1048576ull;
    if (ws_size < 72 * MB) return;
    char* p = (char*)d_ws;
    bf16* qb  = (bf16*)(p + 0 * MB);
    bf16* kb  = (bf16*)(p + 8 * MB);
    bf16* vb  = (bf16*)(p + 16 * MB);
    bf16* Wqb = (bf16*)(p + 24 * MB);
    bf16* Wkb = (bf16*)(p + 26 * MB);
    bf16* Wvb = (bf16*)(p + 28 * MB);
    bf16* Wob = (bf16*)(p + 30 * MB);
    bf16* Qh  = (bf16*)(p + 32 * MB);
    bf16* Kh  = (bf16*)(p + 40 * MB);
    bf16* Vt  = (bf16*)(p + 48 * MB);
    bf16* Yb  = (bf16*)(p + 56 * MB);
    float* ct = (float*)(p + 64 * MB);
    float* st = (float*)(p + 68 * MB);

    CvtArgs ca;
    ca.src[0] = q;  ca.dst[0] = (BH8*)qb;
    ca.src[1] = k;  ca.dst[1] = (BH8*)kb;
    ca.src[2] = v;  ca.dst[2] = (BH8*)vb;
    ca.src[3] = Wq; ca.dst[3] = (BH8*)Wqb;
    ca.src[4] = Wk; ca.dst[4] = (BH8*)Wkb;
    ca.src[5] = Wv; ca.dst[5] = (BH8*)Wvb;
    ca.src[6] = Wo; ca.dst[6] = (BH8*)Wob;
    cvt_all<<<8192, 256, 0, stream>>>(ca);
    rope_tables<<<4096, 256, 0, stream>>>(ct, st);

    ProjArgs pa;
    pa.A[0] = qb;  pa.A[1] = kb;  pa.A[2] = vb;
    pa.W[0] = Wqb; pa.W[1] = Wkb; pa.W[2] = Wvb;
    pa.out[0] = Qh; pa.out[1] = Kh; pa.out[2] = Vt;
    pa.mode[0] = 1; pa.mode[1] = 2; pa.mode[2] = 3;
    gemm_bt<4><<<dim3(8, 32, 3), 256, 0, stream>>>(pa, ct, st, nullptr);

    attn_fwd<<<dim3(16, 32), 256, 0, stream>>>(Qh, Kh, Vt, Yb);

    // final projection: 64x128 tiles -> 512 blocks -> 2 blocks/CU
    ProjArgs pf;
    pf.A[0] = Yb; pf.A[1] = Yb; pf.A[2] = Yb;
    pf.W[0] = Wob; pf.W[1] = Wob; pf.W[2] = Wob;
    pf.out[0] = d_out; pf.out[1] = d_out; pf.out[2] = d_out;
    pf.mode[0] = 0; pf.mode[1] = 0; pf.mode[2] = 0;
    gemm_bt<2><<<dim3(8, 64, 1), 256, 0, stream>>>(pf, ct, st, bo);
}

// Round 6
// 150.181 us; speedup vs baseline: 1.3559x; 1.3559x over previous
//
#include <hip/hip_runtime.h>
#include <hip/hip_bf16.h>

using bf16 = __hip_bfloat16;
using bf16x8 = __attribute__((ext_vector_type(8))) short;
using f32x4 = __attribute__((ext_vector_type(4))) float;

#define LOG2E 1.44269504088896f

__device__ __forceinline__ void gload_lds16(const void* g, void* lds) {
    __builtin_amdgcn_global_load_lds(
        (const __attribute__((address_space(1))) void*)g,
        (__attribute__((address_space(3))) void*)lds, 16, 0, 0);
}

// ---------------- fused fp32 -> bf16 convert for all 7 tensors --------
struct __align__(16) BH8 { bf16 h[8]; };
struct __align__(8)  BH4 { bf16 h[4]; };

struct CvtArgs { const float* src[7]; BH8* dst[7]; };

// vec8 counts: q,k,v = 524288 each (pow2), W_* = 131072 each (pow2)
__global__ __launch_bounds__(256) void cvt_all(CvtArgs ca) {
    int i = blockIdx.x * 256 + threadIdx.x;   // vec8 index, total 2097152
    const float* src; BH8* dst; int off;
    if (i < 3 * 524288) {
        int w = i >> 19; off = i & 524287;
        src = ca.src[w]; dst = ca.dst[w];
    } else {
        int j = i - 3 * 524288;
        int w = 3 + (j >> 17); off = j & 131071;
        src = ca.src[w]; dst = ca.dst[w];
    }
    const float4* p = (const float4*)src + (size_t)off * 2;
    float4 a = p[0], b = p[1];
    BH8 r;
    r.h[0] = __float2bfloat16(a.x); r.h[1] = __float2bfloat16(a.y);
    r.h[2] = __float2bfloat16(a.z); r.h[3] = __float2bfloat16(a.w);
    r.h[4] = __float2bfloat16(b.x); r.h[5] = __float2bfloat16(b.y);
    r.h[6] = __float2bfloat16(b.z); r.h[7] = __float2bfloat16(b.w);
    dst[off] = r;
}

// ---------------- RoPE tables: cos/sin per (s, pair i) ----------------
__global__ __launch_bounds__(256) void rope_tables(float* __restrict__ ct,
                                                   float* __restrict__ st) {
    int idx = blockIdx.x * 256 + threadIdx.x;
    if (idx >= 2048 * 512) return;
    int s = idx >> 9, i = idx & 511;
    // theta = 10000^(-2i/1024) = exp2(i * (-2/1024)*log2(10000))
    float theta = exp2f((float)i * -0.0259525632413075f);
    float ang = (float)s * theta;
    ct[idx] = cosf(ang);
    st[idx] = sinf(ang);
}

// ---------------- GEMM C = A * W^T (A:[M][1024], W:[1024][1024]) ------
// MF = m-fragments per wave; block tile = (MF*32) x 128, 4 waves (2m x 2n)
// mode 0: +bias, fp32 out [M][1024]
// mode 1: RoPE + (0.125*log2e) scale, bf16 head-split out [bh][s][64]  (Q)
// mode 2: RoPE,               bf16 head-split out [bh][s][64]   (K)
// mode 3: plain,              bf16 transposed  out [bh][64][s]  (V^T)
struct ProjArgs {
    const bf16* A[3];
    const bf16* W[3];
    void* out[3];
    int mode[3];
};

template <int MF>
__global__ __launch_bounds__(256, 2) void gemm_bt(ProjArgs pa,
        const float* __restrict__ ct, const float* __restrict__ st,
        const float* __restrict__ bias) {
    constexpr int Kd = 1024;
    constexpr int BM = MF * 32;
    __shared__ __align__(16) bf16 As[BM * 32];
    __shared__ __align__(16) bf16 Bs[128 * 32];
    const int z = blockIdx.z;
    const bf16* __restrict__ A = pa.A[z];
    const bf16* __restrict__ W = pa.W[z];
    const int mode = pa.mode[z];
    const int tid = threadIdx.x, wid = tid >> 6, lane = tid & 63;
    const int g = lane >> 4, l15 = lane & 15;
    const int wm = wid >> 1, wn = wid & 1;
    const int m0 = blockIdx.y * BM, n0 = blockIdx.x * 128;
    f32x4 acc[MF][4] = {};
    const int sbyte = wid * 1024 + lane * 16;

    for (int kb = 0; kb < Kd; kb += 32) {
        __syncthreads();
#pragma unroll
        for (int r = 0; r < MF / 2; ++r) {
            int byte = sbyte + r * 4096;
            int row = byte >> 6, cb = byte & 63;
            int csrc = cb ^ (((row >> 1) & 3) << 4);   // XOR-swizzle on global source
            gload_lds16((const char*)(A + (size_t)(m0 + row) * Kd + kb) + csrc,
                        (char*)As + wid * 1024 + r * 4096);
        }
#pragma unroll
        for (int r = 0; r < 2; ++r) {
            int byte = sbyte + r * 4096;
            int row = byte >> 6, cb = byte & 63;
            int csrc = cb ^ (((row >> 1) & 3) << 4);
            gload_lds16((const char*)(W + (size_t)(n0 + row) * Kd + kb) + csrc,
                        (char*)Bs + wid * 1024 + r * 4096);
        }
        __syncthreads();
        bf16x8 af[MF], bw[4];
#pragma unroll
        for (int i = 0; i < MF; ++i) {
            int ra = wm * (MF * 16) + i * 16 + l15;
            af[i] = *(const bf16x8*)((const char*)As + ra * 64 +
                                     ((g * 16) ^ (((ra >> 1) & 3) << 4)));
        }
#pragma unroll
        for (int j = 0; j < 4; ++j) {
            int rb = wn * 64 + j * 16 + l15;
            bw[j] = *(const bf16x8*)((const char*)Bs + rb * 64 +
                                     ((g * 16) ^ (((rb >> 1) & 3) << 4)));
        }
#pragma unroll
        for (int i = 0; i < MF; ++i)
#pragma unroll
            for (int j = 0; j < 4; ++j)
                acc[i][j] = __builtin_amdgcn_mfma_f32_16x16x32_bf16(af[i], bw[j], acc[i][j], 0, 0, 0);
    }

    if (mode == 0) {
        float* out = (float*)pa.out[z];
#pragma unroll
        for (int i = 0; i < MF; ++i) {
            int row = m0 + wm * (MF * 16) + i * 16 + g * 4;
#pragma unroll
            for (int j = 0; j < 4; ++j) {
                int col = n0 + wn * 64 + j * 16 + l15;
                float bv = bias[col];
#pragma unroll
                for (int r = 0; r < 4; ++r)
                    out[(size_t)(row + r) * 1024 + col] = acc[i][j][r] + bv;
            }
        }
    } else if (mode == 3) {
        bf16* out = (bf16*)pa.out[z];
#pragma unroll
        for (int i = 0; i < MF; ++i) {
            int m = m0 + wm * (MF * 16) + i * 16 + g * 4;
            int b = m >> 11, s = m & 2047;
#pragma unroll
            for (int j = 0; j < 4; ++j) {
                int col = n0 + wn * 64 + j * 16 + l15;
                int h = col >> 6, dv = col & 63;
                BH4 pk;
#pragma unroll
                for (int r = 0; r < 4; ++r) pk.h[r] = __float2bfloat16(acc[i][j][r]);
                *(BH4*)(out + (((size_t)(b * 16 + h)) * 64 + dv) * 2048 + s) = pk;
            }
        }
    } else {  // RoPE modes
        bf16* out = (bf16*)pa.out[z];
        float scl = (mode == 1) ? (0.125f * LOG2E) : 1.0f;
#pragma unroll
        for (int i = 0; i < MF; ++i) {
            int mrow = m0 + wm * (MF * 16) + i * 16 + g * 4;
#pragma unroll
            for (int j = 0; j < 4; ++j) {
                int col = n0 + wn * 64 + j * 16 + l15;
                int ci = col >> 1;
                float sgn = (col & 1) ? -1.0f : 1.0f;
                int h = col >> 6, dv = col & 63;
#pragma unroll
                for (int r = 0; r < 4; ++r) {
                    int m = mrow + r;
                    int b = m >> 11, s = m & 2047;
                    float vv = acc[i][j][r];
                    float pv = __shfl_xor(vv, 1);     // paired column lives in lane^1
                    float c = ct[s * 512 + ci], sn = st[s * 512 + ci];
                    float o = (vv * c + sgn * sn * pv) * scl;
                    out[(((size_t)(b * 16 + h)) * 2048 + s) * 64 + dv] = __float2bfloat16(o);
                }
            }
        }
    }
}

// -------- flash attention: LDS K/V (dbuf) + register-resident P --------
// 2 waves x 32 q-rows/block, grid (32,32)=1024 blocks -> 4 blocks/CU.
// Swapped QK^T (S^T = mfma(K,Q)) with K rows stored PERMUTED in LDS so the
// S^T accumulator is exactly the PV A-operand after in-register exp2+pack.
// LDS row L holds physical K row f(L) = 32*(L>>5) + 8*((L>>2)&3)
//                                      + 4*((L>>4)&1) + (L&3);
// then A-frag kfr (LDS rows kfr*16+l15) reg r = P[q][32*(kfr>>1)+8g+4*(kfr&1)+r],
// i.e. PV k-chunk ch: elems 0-3 = frag 2ch regs 0-3, elems 4-7 = frag 2ch+1.
// Fixed-max softmax (m=0), lane-local l partials, one reduce at the end.
__global__ __launch_bounds__(128, 2) void attn_fwd(
        const bf16* __restrict__ Qh, const bf16* __restrict__ Kh,
        const bf16* __restrict__ Vt, bf16* __restrict__ Y) {
    __shared__ __align__(16) bf16 Ks[2][64 * 64];   // permuted-row K tile
    __shared__ __align__(16) bf16 Vs[2][64 * 64];   // V^T tile [dv][k]
    const int tid = threadIdx.x, wid = tid >> 6, lane = tid & 63;
    const int g = lane >> 4, l15 = lane & 15;
    // XCD swizzle: each XCD gets 4 consecutive bh (K/V 2MB < 4MB L2)
    const int lin = blockIdx.y * 32 + blockIdx.x;   // 0..1023
    const int swz = (lin & 7) * 128 + (lin >> 3);
    const int bh = swz >> 5, qt = swz & 31;
    const int q0 = qt * 64 + wid * 32;
    const bf16* Qb = Qh + (size_t)bh * 2048 * 64;
    const bf16* Kb = Kh + (size_t)bh * 2048 * 64;
    const bf16* Vb = Vt + (size_t)bh * 64 * 2048;

    // Q fragments (B-operand): lane l15 = q, elems = d-chunk
    bf16x8 aq[2][2];
#pragma unroll
    for (int qfr = 0; qfr < 2; ++qfr)
#pragma unroll
        for (int kk = 0; kk < 2; ++kk)
            aq[qfr][kk] = *(const bf16x8*)(Qb + (size_t)(q0 + qfr * 16 + l15) * 64 + kk * 32 + g * 8);

    f32x4 yacc[2][4] = {};          // [qfr][dn]: row q=qfr*16+4g+r, col dv=dn*16+l15
    float lrow[2] = {0.f, 0.f};     // per-lane partial l for q = qfr*16+l15

    // staging: 4 issues x (K,V); byte = wid*1024 + lane*16 + i*2048
    int srow[4], csrc[4], kphys[4];
#pragma unroll
    for (int i = 0; i < 4; ++i) {
        int byte = wid * 1024 + lane * 16 + i * 2048;
        srow[i] = byte >> 7;
        csrc[i] = (byte & 127) ^ ((srow[i] & 7) << 4);
        int L = srow[i];
        kphys[i] = ((L >> 5) << 5) + (((L >> 2) & 3) << 3) + (((L >> 4) & 1) << 2) + (L & 3);
    }

#define STAGE(T, BUF)                                                           \
    do {                                                                        \
        _Pragma("unroll")                                                       \
        for (int i = 0; i < 4; ++i) {                                           \
            gload_lds16((const char*)(Kb + (size_t)((T) * 64 + kphys[i]) * 64) + csrc[i], \
                        (char*)&Ks[BUF][0] + wid * 1024 + i * 2048);            \
            gload_lds16((const char*)(Vb + (size_t)srow[i] * 2048 + (T) * 64) + csrc[i],  \
                        (char*)&Vs[BUF][0] + wid * 1024 + i * 2048);            \
        }                                                                       \
    } while (0)

    STAGE(0, 0);

    for (int t = 0; t < 32; ++t) {
        __syncthreads();                 // stage(t) landed (compiler drains vmcnt)
        if (t < 31) STAGE(t + 1, (t + 1) & 1);
        const char* Kst = (const char*)&Ks[t & 1][0];
        const char* Vst = (const char*)&Vs[t & 1][0];

        // QK^T swapped: sacc[kfr][qfr] lane(l15=q, g) reg r =
        //   S[q][ k = 32*(kfr>>1) + 8g + 4*(kfr&1) + r ]   (x 0.125*log2e in Q)
        f32x4 sacc[4][2] = {};
#pragma unroll
        for (int kk = 0; kk < 2; ++kk) {
            bf16x8 kf[4];
#pragma unroll
            for (int kfr = 0; kfr < 4; ++kfr)
                kf[kfr] = *(const bf16x8*)(Kst + (kfr * 16 + l15) * 128 +
                                           ((kk * 64 + g * 16) ^ ((l15 & 7) << 4)));
#pragma unroll
            for (int kfr = 0; kfr < 4; ++kfr)
#pragma unroll
                for (int qfr = 0; qfr < 2; ++qfr)
                    sacc[kfr][qfr] = __builtin_amdgcn_mfma_f32_16x16x32_bf16(
                        kf[kfr], aq[qfr][kk], sacc[kfr][qfr], 0, 0, 0);
        }

        // softmax numerator in-register: p = 2^s, pack into PV A-frags
        bf16x8 ap[2][2];   // [qfr][k-chunk]
#pragma unroll
        for (int qfr = 0; qfr < 2; ++qfr)
#pragma unroll
            for (int ch = 0; ch < 2; ++ch) {
                bf16 hh[8];
#pragma unroll
                for (int r = 0; r < 4; ++r) {
                    float x = exp2f(sacc[2 * ch][qfr][r]);
                    lrow[qfr] += x;
                    hh[r] = __float2bfloat16(x);
                }
#pragma unroll
                for (int r = 0; r < 4; ++r) {
                    float x = exp2f(sacc[2 * ch + 1][qfr][r]);
                    lrow[qfr] += x;
                    hh[4 + r] = __float2bfloat16(x);
                }
                ap[qfr][ch] = *(const bf16x8*)hh;
            }

        // PV: yacc += P * V  (B-frag: lane l15 = dv col, elems = k-chunk)
#pragma unroll
        for (int ch = 0; ch < 2; ++ch) {
            bf16x8 bv[4];
#pragma unroll
            for (int dn = 0; dn < 4; ++dn)
                bv[dn] = *(const bf16x8*)(Vst + (dn * 16 + l15) * 128 +
                                          ((ch * 64 + g * 16) ^ ((l15 & 7) << 4)));
#pragma unroll
            for (int qfr = 0; qfr < 2; ++qfr)
#pragma unroll
                for (int dn = 0; dn < 4; ++dn)
                    yacc[qfr][dn] = __builtin_amdgcn_mfma_f32_16x16x32_bf16(
                        ap[qfr][ch], bv[dn], yacc[qfr][dn], 0, 0, 0);
        }
    }
#undef STAGE

    // epilogue: reduce l across g-groups, redistribute, normalize, write
    const int b = bh >> 4, h = bh & 15;
#pragma unroll
    for (int qfr = 0; qfr < 2; ++qfr) {
        float ls = lrow[qfr];
        ls += __shfl_xor(ls, 16);
        ls += __shfl_xor(ls, 32);       // all lanes: l for q = qfr*16 + l15
#pragma unroll
        for (int r = 0; r < 4; ++r) {
            float lv = __shfl(ls, g * 4 + r);   // l for q = qfr*16 + g*4 + r
            float inv = 1.0f / lv;
            int s = q0 + qfr * 16 + g * 4 + r;
            bf16* yp = Y + ((size_t)(b * 2048 + s)) * 1024 + h * 64;
#pragma unroll
            for (int dn = 0; dn < 4; ++dn)
                yp[dn * 16 + l15] = __float2bfloat16(yacc[qfr][dn][r] * inv);
        }
    }
}

// ---------------------------------------------------------------------
extern "C" void kernel_launch(void* const* d_in, const int* in_sizes, int n_in,
                              void* d_out, int out_size, void* d_ws, size_t ws_size,
                              hipStream_t stream) {
    const float* q  = (const float*)d_in[0];
    const float* k  = (const float*)d_in[1];
    const float* v  = (const float*)d_in[2];
    const float* Wq = (const float*)d_in[3];
    const float* Wk = (const float*)d_in[4];
    const float* Wv = (const float*)d_in[5];
    const float* Wo = (const float*)d_in[6];
    const float* bo = (const float*)d_in[7];

    const size_t MB = 1048576ull;
    if (ws_size < 72 * MB) return;
    char* p = (char*)d_ws;
    bf16* qb  = (bf16*)(p + 0 * MB);
    bf16* kb  = (bf16*)(p + 8 * MB);
    bf16* vb  = (bf16*)(p + 16 * MB);
    bf16* Wqb = (bf16*)(p + 24 * MB);
    bf16* Wkb = (bf16*)(p + 26 * MB);
    bf16* Wvb = (bf16*)(p + 28 * MB);
    bf16* Wob = (bf16*)(p + 30 * MB);
    bf16* Qh  = (bf16*)(p + 32 * MB);
    bf16* Kh  = (bf16*)(p + 40 * MB);
    bf16* Vt  = (bf16*)(p + 48 * MB);
    bf16* Yb  = (bf16*)(p + 56 * MB);
    float* ct = (float*)(p + 64 * MB);
    float* st = (float*)(p + 68 * MB);

    CvtArgs ca;
    ca.src[0] = q;  ca.dst[0] = (BH8*)qb;
    ca.src[1] = k;  ca.dst[1] = (BH8*)kb;
    ca.src[2] = v;  ca.dst[2] = (BH8*)vb;
    ca.src[3] = Wq; ca.dst[3] = (BH8*)Wqb;
    ca.src[4] = Wk; ca.dst[4] = (BH8*)Wkb;
    ca.src[5] = Wv; ca.dst[5] = (BH8*)Wvb;
    ca.src[6] = Wo; ca.dst[6] = (BH8*)Wob;
    cvt_all<<<8192, 256, 0, stream>>>(ca);
    rope_tables<<<4096, 256, 0, stream>>>(ct, st);

    ProjArgs pa;
    pa.A[0] = qb;  pa.A[1] = kb;  pa.A[2] = vb;
    pa.W[0] = Wqb; pa.W[1] = Wkb; pa.W[2] = Wvb;
    pa.out[0] = Qh; pa.out[1] = Kh; pa.out[2] = Vt;
    pa.mode[0] = 1; pa.mode[1] = 2; pa.mode[2] = 3;
    gemm_bt<4><<<dim3(8, 32, 3), 256, 0, stream>>>(pa, ct, st, nullptr);

    attn_fwd<<<dim3(32, 32), 128, 0, stream>>>(Qh, Kh, Vt, Yb);

    // final projection: 64x128 tiles -> 512 blocks -> 2 blocks/CU
    ProjArgs pf;
    pf.A[0] = Yb; pf.A[1] = Yb; pf.A[2] = Yb;
    pf.W[0] = Wob; pf.W[1] = Wob; pf.W[2] = Wob;
    pf.out[0] = d_out; pf.out[1] = d_out; pf.out[2] = d_out;
    pf.mode[0] = 0; pf.mode[1] = 0; pf.mode[2] = 0;
    gemm_bt<2><<<dim3(8, 64, 1), 256, 0, stream>>>(pf, ct, st, bo);
}